// Round 1
// baseline (112.307 us; speedup 1.0000x reference)
//
#include <hip/hip_runtime.h>
#include <hip/hip_bf16.h>

#define NN  512
#define CC  64
#define HID 256
#define H4  (HID/4)
#define PSTRIDE (NN*HID)
#define PROWS 4                  // 4 rows/block: halves W1 L2 re-read traffic
#define NB_BORDER 256            // border blocks, dispatched first

typedef short  bf16x8 __attribute__((ext_vector_type(8)));
typedef float  f32x4  __attribute__((ext_vector_type(4)));

// ---------------------------------------------------------------------------
// Kernel 1: 6 small projections. P slots: [PA,PC,PE,PB,PD,PF], b1 in PA.
// ---------------------------------------------------------------------------
__global__ __launch_bounds__(256) void proj_kernel(
    const float* __restrict__ xl, const float* __restrict__ xr,
    const float* __restrict__ W1, const float* __restrict__ b1,
    float* __restrict__ P)
{
  const int side = blockIdx.y;
  const int i0   = blockIdx.x * PROWS;
  const int h    = threadIdx.x;
  const float* __restrict__ x = side ? xr : xl;

  __shared__ float xs[PROWS][CC];
  // PROWS*CC == 256 == blockDim.x
  xs[threadIdx.x >> 6][threadIdx.x & 63] = x[i0 * CC + threadIdx.x];
  __syncthreads();

  float acc0[PROWS], acc1[PROWS], acc2[PROWS];
#pragma unroll
  for (int r = 0; r < PROWS; r++) { acc0[r] = 0.f; acc1[r] = 0.f; acc2[r] = 0.f; }

  const int base = side ? CC : 0;
  const float* __restrict__ w0p = W1 + (base      ) * HID + h;
  const float* __restrict__ w1p = W1 + (base + 128) * HID + h;
  const float* __restrict__ w2p = W1 + (base + 256) * HID + h;
#pragma unroll 8
  for (int c = 0; c < CC; c++) {
    float w0 = w0p[c * HID];
    float w1 = w1p[c * HID];
    float w2 = w2p[c * HID];
#pragma unroll
    for (int r = 0; r < PROWS; r++) {
      float xv = xs[r][c];
      acc0[r] = fmaf(xv, w0, acc0[r]);
      acc1[r] = fmaf(xv, w1, acc1[r]);
      acc2[r] = fmaf(xv, w2, acc2[r]);
    }
  }

  float* __restrict__ O0 = P + (side ? 3 : 0) * PSTRIDE;
  float* __restrict__ O1 = P + (side ? 4 : 1) * PSTRIDE;
  float* __restrict__ O2 = P + (side ? 5 : 2) * PSTRIDE;
  const float bb = side ? 0.f : b1[h];
#pragma unroll
  for (int r = 0; r < PROWS; r++) {
    O0[(i0 + r) * HID + h] = acc0[r] + bb;
    O1[(i0 + r) * HID + h] = acc1[r];
    O2[(i0 + r) * HID + h] = acc2[r];
  }
}

// ---------------------------------------------------------------------------
// Kernel 2: prep. U_i = PA[i]+PC[i-1]+PE[i+1], V_j = PB[j]+PD[j+1]+PF[j-1].
// ---------------------------------------------------------------------------
__global__ __launch_bounds__(256) void prep_kernel(
    const float* __restrict__ P,
    float* __restrict__ Uf, float* __restrict__ Vt,
    unsigned short* __restrict__ Ubf, unsigned short* __restrict__ Vbf,
    float* __restrict__ rowstat)
{
  const int r = blockIdx.x, h = threadIdx.x;
  const float* __restrict__ PA = P;
  const float* __restrict__ PC = P + 1 * PSTRIDE;
  const float* __restrict__ PE = P + 2 * PSTRIDE;
  const float* __restrict__ PB = P + 3 * PSTRIDE;
  const float* __restrict__ PD = P + 4 * PSTRIDE;
  const float* __restrict__ PF = P + 5 * PSTRIDE;

  float u = PA[r * HID + h] + PC[(r - 1) * HID + h] + PE[(r + 1) * HID + h];
  float v = PB[r * HID + h] + PD[(r + 1) * HID + h] + PF[(r - 1) * HID + h];
  Uf[r * HID + h] = u;
  Vt[((h >> 2) * NN + r) * 4 + (h & 3)] = v;
  __hip_bfloat16 ub = __float2bfloat16(u), vb = __float2bfloat16(v);
  Ubf[r * HID + h] = *(unsigned short*)&ub;
  Vbf[r * HID + h] = *(unsigned short*)&vb;

  float u2 = u * u, v2 = v * v;
#pragma unroll
  for (int k = 32; k >= 1; k >>= 1) {
    u  += __shfl_xor(u,  k, 64);
    u2 += __shfl_xor(u2, k, 64);
    v  += __shfl_xor(v,  k, 64);
    v2 += __shfl_xor(v2, k, 64);
  }
  __shared__ float red[4][4];
  const int w = h >> 6;
  if ((h & 63) == 0) { red[w][0] = u; red[w][1] = u2; red[w][2] = v; red[w][3] = v2; }
  __syncthreads();
  if (h < 4)
    rowstat[h * NN + r] = red[0][h] + red[1][h] + red[2][h] + red[3][h];
}

// ---------------------------------------------------------------------------
// Kernel 3: Cross[i,j] = sum_h U[i,h]*V[j,h] via bf16 MFMA 16x16x32.
// ---------------------------------------------------------------------------
__global__ __launch_bounds__(256) void cross_kernel(
    const unsigned short* __restrict__ Ubf,
    const unsigned short* __restrict__ Vbf,
    float* __restrict__ Cross)
{
  const int wave = threadIdx.x >> 6, lane = threadIdx.x & 63;
  const int t  = blockIdx.x * 4 + wave;
  const int ti = t >> 5, tj = t & 31;
  const int i0 = ti * 16, j0 = tj * 16;
  const int rc = lane & 15, kb = (lane >> 4) * 8;

  f32x4 acc = {0.f, 0.f, 0.f, 0.f};
#pragma unroll
  for (int k = 0; k < HID; k += 32) {
    bf16x8 a = *(const bf16x8*)(Ubf + (size_t)(i0 + rc) * HID + k + kb);
    bf16x8 b = *(const bf16x8*)(Vbf + (size_t)(j0 + rc) * HID + k + kb);
    acc = __builtin_amdgcn_mfma_f32_16x16x32_bf16(a, b, acc, 0, 0, 0);
  }
  const int orow = (lane >> 4) * 4, ocol = lane & 15;
#pragma unroll
  for (int r = 0; r < 4; r++)
    Cross[(size_t)(i0 + orow + r) * NN + j0 + ocol] = acc[r];
}

__device__ __forceinline__ float celu1(float x) {
  float e = __expf(x) - 1.f;
  return x > 0.f ? x : e;
}

// ---------------------------------------------------------------------------
// Kernel 4: pair epilogue. Interior now processes TWO rows per block:
// thread owns pairs (i0,j) and (i1,j), sharing the V[j] float4 stream and
// amortizing the uniform {gamma,beta,W2} LDS reads across 2 pairs
// (uniform ds_read_b128 per pair-iter: 4 -> 2.5; V L2 traffic halved).
// Arithmetic order per pair unchanged -> bit-identical interior output.
// ---------------------------------------------------------------------------
__global__ __launch_bounds__(256) void pair_kernel(
    const float* __restrict__ P,
    const float* __restrict__ Uf, const float* __restrict__ Vt,
    const float* __restrict__ Cross, const float* __restrict__ rowstat,
    const float* __restrict__ gamma, const float* __restrict__ beta,
    const float* __restrict__ W2, const float* __restrict__ b2,
    float* __restrict__ out)
{
  const int wave = threadIdx.x >> 6, lane = threadIdx.x & 63;
  const float b2s = b2[0];

  if (blockIdx.x >= NB_BORDER) {
    const int bx = blockIdx.x - NB_BORDER;        // 0..509
    const int bi = bx >> 1;                       // 0..254
    const int i0 = 1 + (bi << 1);                 // 1,3,..,509
    const int i1 = i0 + 1;                        // 2,4,..,510
    const int jj = ((bx & 1) << 8) + threadIdx.x; // 0..511
    const int j  = jj < 1 ? 1 : (jj > 510 ? 510 : jj);

    __shared__ __align__(16) float Gs[HID], Bs[HID], Ws[HID], U0s[HID], U1s[HID];
    Gs[threadIdx.x]  = gamma[threadIdx.x];
    Bs[threadIdx.x]  = beta[threadIdx.x];
    Ws[threadIdx.x]  = W2[threadIdx.x];
    U0s[threadIdx.x] = Uf[i0 * HID + threadIdx.x];
    U1s[threadIdx.x] = Uf[i1 * HID + threadIdx.x];
    __syncthreads();

    const float inv = 1.f / HID;
    const float sV  = rowstat[2 * NN + j], sV2 = rowstat[3 * NN + j];

    const float mu0 = (rowstat[0 * NN + i0] + sV) * inv;
    const float tq0 = fmaf(2.f, Cross[i0 * NN + j], rowstat[1 * NN + i0] + sV2) * inv;
    const float rs0 = rsqrtf(tq0 - mu0 * mu0 + 1e-5f);
    const float mr0 = -mu0 * rs0;

    const float mu1 = (rowstat[0 * NN + i1] + sV) * inv;
    const float tq1 = fmaf(2.f, Cross[i1 * NN + j], rowstat[1 * NN + i1] + sV2) * inv;
    const float rs1 = rsqrtf(tq1 - mu1 * mu1 + 1e-5f);
    const float mr1 = -mu1 * rs1;

    float a0x = 0.f, a0y = 0.f;   // pair (i0,j): x/z and y/w lanes
    float a1x = 0.f, a1y = 0.f;   // pair (i1,j)

    const float4* __restrict__ Vp = (const float4*)Vt;    // [hb*NN + j]
    const float4* __restrict__ G4 = (const float4*)Gs;
    const float4* __restrict__ B4 = (const float4*)Bs;
    const float4* __restrict__ W4 = (const float4*)Ws;
    const float4* __restrict__ U04 = (const float4*)U0s;
    const float4* __restrict__ U14 = (const float4*)U1s;

#pragma unroll 4
    for (int hb = 0; hb < H4; hb++) {
      const float4 v4  = Vp[hb * NN + j];
      const float4 g   = G4[hb];
      const float4 be4 = B4[hb];
      const float4 w4  = W4[hb];
      const float4 u0  = U04[hb];
      const float4 u1  = U14[hb];
      {
        const float n0 = fmaf(fmaf(v4.x + u0.x, rs0, mr0), g.x, be4.x);
        a0x = fmaf(celu1(n0), w4.x, a0x);
        const float n1 = fmaf(fmaf(v4.x + u1.x, rs1, mr1), g.x, be4.x);
        a1x = fmaf(celu1(n1), w4.x, a1x);
      }
      {
        const float n0 = fmaf(fmaf(v4.y + u0.y, rs0, mr0), g.y, be4.y);
        a0y = fmaf(celu1(n0), w4.y, a0y);
        const float n1 = fmaf(fmaf(v4.y + u1.y, rs1, mr1), g.y, be4.y);
        a1y = fmaf(celu1(n1), w4.y, a1y);
      }
      {
        const float n0 = fmaf(fmaf(v4.z + u0.z, rs0, mr0), g.z, be4.z);
        a0x = fmaf(celu1(n0), w4.z, a0x);
        const float n1 = fmaf(fmaf(v4.z + u1.z, rs1, mr1), g.z, be4.z);
        a1x = fmaf(celu1(n1), w4.z, a1x);
      }
      {
        const float n0 = fmaf(fmaf(v4.w + u0.w, rs0, mr0), g.w, be4.w);
        a0y = fmaf(celu1(n0), w4.w, a0y);
        const float n1 = fmaf(fmaf(v4.w + u1.w, rs1, mr1), g.w, be4.w);
        a1y = fmaf(celu1(n1), w4.w, a1y);
      }
    }
    if (jj >= 1 && jj <= 510) {
      out[i0 * NN + jj] = a0x + a0y + b2s;
      out[i1 * NN + jj] = a1x + a1y + b2s;
    }
  } else {
    // ---- border: 2044 pairs spread over 1024 waves (2 pairs each)
    const int gw = blockIdx.x * 4 + wave;              // 0..1023
    const float4* P4 = (const float4*)P;
    const float4* PA = P4 + 0 * (PSTRIDE / 4);
    const float4* PC = P4 + 1 * (PSTRIDE / 4);
    const float4* PE = P4 + 2 * (PSTRIDE / 4);
    const float4* PB = P4 + 3 * (PSTRIDE / 4);
    const float4* PD = P4 + 4 * (PSTRIDE / 4);
    const float4* PF = P4 + 5 * (PSTRIDE / 4);
    const float4 g  = ((const float4*)gamma)[lane];
    const float4 be = ((const float4*)beta)[lane];
    const float4 w2 = ((const float4*)W2)[lane];

#pragma unroll
    for (int tt = 0; tt < 2; tt++) {
      const int p = gw * 2 + tt;
      if (p >= 2044) break;
      int i, j;
      if      (p < 512)  { i = 0;        j = p;        }
      else if (p < 1024) { i = 511;      j = p - 512;  }
      else if (p < 1534) { i = p - 1023; j = 0;        }
      else               { i = p - 1533; j = 511;      }

      const float4 a  = PA[i * H4 + lane];
      const float4 cu = PC[(i - 1) * H4 + lane];
      const float4 ed = PE[(i + 1) * H4 + lane];
      const float4 b  = PB[j * H4 + lane];
      const float4 du = PD[(j + 1) * H4 + lane];
      const float4 fd = PF[(j - 1) * H4 + lane];
      const float mu_m = (i >= 1 && j <= NN - 2) ? 1.f : 0.f;
      const float md_m = (i <= NN - 2 && j >= 1) ? 1.f : 0.f;

      float s0 = fmaf(md_m, ed.x + fd.x, fmaf(mu_m, cu.x + du.x, a.x + b.x));
      float s1 = fmaf(md_m, ed.y + fd.y, fmaf(mu_m, cu.y + du.y, a.y + b.y));
      float s2 = fmaf(md_m, ed.z + fd.z, fmaf(mu_m, cu.z + du.z, a.z + b.z));
      float s3 = fmaf(md_m, ed.w + fd.w, fmaf(mu_m, cu.w + du.w, a.w + b.w));

      float sum = (s0 + s1) + (s2 + s3);
      float ssq = fmaf(s0, s0, fmaf(s1, s1, fmaf(s2, s2, s3 * s3)));
#pragma unroll
      for (int off = 32; off >= 1; off >>= 1) {
        sum += __shfl_xor(sum, off, 64);
        ssq += __shfl_xor(ssq, off, 64);
      }
      const float mu  = sum * (1.f / HID);
      const float var = fmaf(ssq, 1.f / HID, -mu * mu);
      const float rs  = rsqrtf(var + 1e-5f);
      const float mrs = -mu * rs;

      auto nrm = [&](float s, float G, float Bt) {
        return fmaf(fmaf(s, rs, mrs), G, Bt);
      };
      float racc = fmaf(celu1(nrm(s0, g.x, be.x)), w2.x,
                   fmaf(celu1(nrm(s1, g.y, be.y)), w2.y,
                   fmaf(celu1(nrm(s2, g.z, be.z)), w2.z,
                        celu1(nrm(s3, g.w, be.w)) * w2.w)));
#pragma unroll
      for (int off = 32; off >= 1; off >>= 1)
        racc += __shfl_xor(racc, off, 64);
      if (lane == 0) out[i * NN + j] = racc + b2s;
    }
  }
}

extern "C" void kernel_launch(void* const* d_in, const int* in_sizes, int n_in,
                              void* d_out, int out_size, void* d_ws, size_t ws_size,
                              hipStream_t stream)
{
  const float* xl    = (const float*)d_in[0];
  const float* xr    = (const float*)d_in[1];
  const float* W1    = (const float*)d_in[2];
  const float* b1    = (const float*)d_in[3];
  const float* gamma = (const float*)d_in[4];
  const float* beta  = (const float*)d_in[5];
  const float* W2    = (const float*)d_in[6];
  const float* b2    = (const float*)d_in[7];
  float* out = (float*)d_out;

  float* P     = (float*)d_ws;                       // 3 MB
  float* Uf    = P + 6 * PSTRIDE;                    // 0.5 MB
  float* Vt    = Uf + NN * HID;                      // 0.5 MB (transposed V)
  float* Cross = Vt + NN * HID;                      // 1 MB
  unsigned short* Ubf = (unsigned short*)(Cross + NN * NN);
  unsigned short* Vbf = Ubf + NN * HID;
  float* rowstat = (float*)(Vbf + NN * HID);

  proj_kernel<<<dim3(NN / PROWS, 2), 256, 0, stream>>>(xl, xr, W1, b1, P);
  prep_kernel<<<NN, 256, 0, stream>>>(P, Uf, Vt, Ubf, Vbf, rowstat);
  cross_kernel<<<256, 256, 0, stream>>>(Ubf, Vbf, Cross);
  pair_kernel<<<NB_BORDER + 510, 256, 0, stream>>>(P, Uf, Vt, Cross, rowstat,
                                                   gamma, beta, W2, b2, out);
}

// Round 2
// 105.580 us; speedup vs baseline: 1.0637x; 1.0637x over previous
//
#include <hip/hip_runtime.h>
#include <hip/hip_bf16.h>

#define NN  512
#define CC  64
#define HID 256
#define H4  (HID/4)
#define PSTRIDE (NN*HID)
#define PROWS 4                  // 4 rows/block: halves W1 L2 re-read traffic
#define NB_BORDER 256            // border blocks, dispatched first

typedef short  bf16x8 __attribute__((ext_vector_type(8)));
typedef float  f32x4  __attribute__((ext_vector_type(4)));

// ---------------------------------------------------------------------------
// Kernel 1: 6 small projections. P slots: [PA,PC,PE,PB,PD,PF], b1 in PA.
// ---------------------------------------------------------------------------
__global__ __launch_bounds__(256) void proj_kernel(
    const float* __restrict__ xl, const float* __restrict__ xr,
    const float* __restrict__ W1, const float* __restrict__ b1,
    float* __restrict__ P)
{
  const int side = blockIdx.y;
  const int i0   = blockIdx.x * PROWS;
  const int h    = threadIdx.x;
  const float* __restrict__ x = side ? xr : xl;

  __shared__ float xs[PROWS][CC];
  // PROWS*CC == 256 == blockDim.x
  xs[threadIdx.x >> 6][threadIdx.x & 63] = x[i0 * CC + threadIdx.x];
  __syncthreads();

  float acc0[PROWS], acc1[PROWS], acc2[PROWS];
#pragma unroll
  for (int r = 0; r < PROWS; r++) { acc0[r] = 0.f; acc1[r] = 0.f; acc2[r] = 0.f; }

  const int base = side ? CC : 0;
  const float* __restrict__ w0p = W1 + (base      ) * HID + h;
  const float* __restrict__ w1p = W1 + (base + 128) * HID + h;
  const float* __restrict__ w2p = W1 + (base + 256) * HID + h;
#pragma unroll 8
  for (int c = 0; c < CC; c++) {
    float w0 = w0p[c * HID];
    float w1 = w1p[c * HID];
    float w2 = w2p[c * HID];
#pragma unroll
    for (int r = 0; r < PROWS; r++) {
      float xv = xs[r][c];
      acc0[r] = fmaf(xv, w0, acc0[r]);
      acc1[r] = fmaf(xv, w1, acc1[r]);
      acc2[r] = fmaf(xv, w2, acc2[r]);
    }
  }

  float* __restrict__ O0 = P + (side ? 3 : 0) * PSTRIDE;
  float* __restrict__ O1 = P + (side ? 4 : 1) * PSTRIDE;
  float* __restrict__ O2 = P + (side ? 5 : 2) * PSTRIDE;
  const float bb = side ? 0.f : b1[h];
#pragma unroll
  for (int r = 0; r < PROWS; r++) {
    O0[(i0 + r) * HID + h] = acc0[r] + bb;
    O1[(i0 + r) * HID + h] = acc1[r];
    O2[(i0 + r) * HID + h] = acc2[r];
  }
}

// ---------------------------------------------------------------------------
// Kernel 2: prep. U_i = PA[i]+PC[i-1]+PE[i+1], V_j = PB[j]+PD[j+1]+PF[j-1].
// ---------------------------------------------------------------------------
__global__ __launch_bounds__(256) void prep_kernel(
    const float* __restrict__ P,
    float* __restrict__ Uf, float* __restrict__ Vt,
    unsigned short* __restrict__ Ubf, unsigned short* __restrict__ Vbf,
    float* __restrict__ rowstat)
{
  const int r = blockIdx.x, h = threadIdx.x;
  const float* __restrict__ PA = P;
  const float* __restrict__ PC = P + 1 * PSTRIDE;
  const float* __restrict__ PE = P + 2 * PSTRIDE;
  const float* __restrict__ PB = P + 3 * PSTRIDE;
  const float* __restrict__ PD = P + 4 * PSTRIDE;
  const float* __restrict__ PF = P + 5 * PSTRIDE;

  float u = PA[r * HID + h] + PC[(r - 1) * HID + h] + PE[(r + 1) * HID + h];
  float v = PB[r * HID + h] + PD[(r + 1) * HID + h] + PF[(r - 1) * HID + h];
  Uf[r * HID + h] = u;
  Vt[((h >> 2) * NN + r) * 4 + (h & 3)] = v;
  __hip_bfloat16 ub = __float2bfloat16(u), vb = __float2bfloat16(v);
  Ubf[r * HID + h] = *(unsigned short*)&ub;
  Vbf[r * HID + h] = *(unsigned short*)&vb;

  float u2 = u * u, v2 = v * v;
#pragma unroll
  for (int k = 32; k >= 1; k >>= 1) {
    u  += __shfl_xor(u,  k, 64);
    u2 += __shfl_xor(u2, k, 64);
    v  += __shfl_xor(v,  k, 64);
    v2 += __shfl_xor(v2, k, 64);
  }
  __shared__ float red[4][4];
  const int w = h >> 6;
  if ((h & 63) == 0) { red[w][0] = u; red[w][1] = u2; red[w][2] = v; red[w][3] = v2; }
  __syncthreads();
  if (h < 4)
    rowstat[h * NN + r] = red[0][h] + red[1][h] + red[2][h] + red[3][h];
}

// ---------------------------------------------------------------------------
// Kernel 3: Cross[i,j] = sum_h U[i,h]*V[j,h] via bf16 MFMA 16x16x32.
// ---------------------------------------------------------------------------
__global__ __launch_bounds__(256) void cross_kernel(
    const unsigned short* __restrict__ Ubf,
    const unsigned short* __restrict__ Vbf,
    float* __restrict__ Cross)
{
  const int wave = threadIdx.x >> 6, lane = threadIdx.x & 63;
  const int t  = blockIdx.x * 4 + wave;
  const int ti = t >> 5, tj = t & 31;
  const int i0 = ti * 16, j0 = tj * 16;
  const int rc = lane & 15, kb = (lane >> 4) * 8;

  f32x4 acc = {0.f, 0.f, 0.f, 0.f};
#pragma unroll
  for (int k = 0; k < HID; k += 32) {
    bf16x8 a = *(const bf16x8*)(Ubf + (size_t)(i0 + rc) * HID + k + kb);
    bf16x8 b = *(const bf16x8*)(Vbf + (size_t)(j0 + rc) * HID + k + kb);
    acc = __builtin_amdgcn_mfma_f32_16x16x32_bf16(a, b, acc, 0, 0, 0);
  }
  const int orow = (lane >> 4) * 4, ocol = lane & 15;
#pragma unroll
  for (int r = 0; r < 4; r++)
    Cross[(size_t)(i0 + orow + r) * NN + j0 + ocol] = acc[r];
}

__device__ __forceinline__ float celu1(float x) {
  float e = __expf(x) - 1.f;
  return x > 0.f ? x : e;
}

// ---------------------------------------------------------------------------
// Kernel 4: pair epilogue. Interior: one row i per 2 blocks (j split 256+256),
// 512 threads/block = thread-per-pair x 2 h-halves. Each thread runs 32 of the
// 64 float4 h-iterations; halves combine via 1KB LDS. Doubles resident waves
// (~8/SIMD) and halves the per-thread latency chain vs the 256-thread version;
// LDS-read count / V L2 traffic / VALU work unchanged.
// ---------------------------------------------------------------------------
__global__ __launch_bounds__(512) void pair_kernel(
    const float* __restrict__ P,
    const float* __restrict__ Uf, const float* __restrict__ Vt,
    const float* __restrict__ Cross, const float* __restrict__ rowstat,
    const float* __restrict__ gamma, const float* __restrict__ beta,
    const float* __restrict__ W2, const float* __restrict__ b2,
    float* __restrict__ out)
{
  const int wave = threadIdx.x >> 6, lane = threadIdx.x & 63;
  const float b2s = b2[0];

  if (blockIdx.x >= NB_BORDER) {
    const int bx = blockIdx.x - NB_BORDER;        // 0..1019
    const int i  = 1 + (bx >> 1);                 // 1..510
    const int tj = threadIdx.x & 255;             // pair slot within j-half
    const int hh = threadIdx.x >> 8;              // 0 or 1: h-half
    const int jj = ((bx & 1) << 8) + tj;          // 0..511
    const int j  = jj < 1 ? 1 : (jj > 510 ? 510 : jj);

    __shared__ float4 K4s[HID];
    __shared__ float  partial[256];
    if (threadIdx.x < HID)
      K4s[threadIdx.x] = make_float4(gamma[threadIdx.x], beta[threadIdx.x],
                                     W2[threadIdx.x], Uf[i * HID + threadIdx.x]);
    __syncthreads();

    const float mu  = (rowstat[0 * NN + i] + rowstat[2 * NN + j]) * (1.f / HID);
    const float tq  = fmaf(2.f, Cross[i * NN + j],
                           rowstat[1 * NN + i] + rowstat[3 * NN + j]) * (1.f / HID);
    const float rs  = rsqrtf(tq - mu * mu + 1e-5f);
    const float mrs = -mu * rs;

    float racc0 = 0.f, racc1 = 0.f;
    const float4* __restrict__ Vp = (const float4*)Vt;   // [hb*NN + j]
    const int hb0 = hh << 5;                             // 0 or 32
#pragma unroll 8
    for (int hb = hb0; hb < hb0 + 32; hb++) {
      const float4 v4 = Vp[hb * NN + j];
      {
        const float4 K = K4s[hb * 4 + 0];
        const float n = fmaf(fmaf(v4.x + K.w, rs, mrs), K.x, K.y);
        racc0 = fmaf(celu1(n), K.z, racc0);
      }
      {
        const float4 K = K4s[hb * 4 + 1];
        const float n = fmaf(fmaf(v4.y + K.w, rs, mrs), K.x, K.y);
        racc1 = fmaf(celu1(n), K.z, racc1);
      }
      {
        const float4 K = K4s[hb * 4 + 2];
        const float n = fmaf(fmaf(v4.z + K.w, rs, mrs), K.x, K.y);
        racc0 = fmaf(celu1(n), K.z, racc0);
      }
      {
        const float4 K = K4s[hb * 4 + 3];
        const float n = fmaf(fmaf(v4.w + K.w, rs, mrs), K.x, K.y);
        racc1 = fmaf(celu1(n), K.z, racc1);
      }
    }
    const float r = racc0 + racc1;
    if (hh == 1) partial[tj] = r;
    __syncthreads();
    if (hh == 0 && jj >= 1 && jj <= 510)
      out[i * NN + jj] = r + partial[tj] + b2s;
  } else {
    // ---- border: 2044 pairs, 8 waves/block x 256 blocks -> 1 pair per wave
    const int gw = blockIdx.x * 8 + wave;              // 0..2047
    const float4* P4 = (const float4*)P;
    const float4* PA = P4 + 0 * (PSTRIDE / 4);
    const float4* PC = P4 + 1 * (PSTRIDE / 4);
    const float4* PE = P4 + 2 * (PSTRIDE / 4);
    const float4* PB = P4 + 3 * (PSTRIDE / 4);
    const float4* PD = P4 + 4 * (PSTRIDE / 4);
    const float4* PF = P4 + 5 * (PSTRIDE / 4);
    const float4 g  = ((const float4*)gamma)[lane];
    const float4 be = ((const float4*)beta)[lane];
    const float4 w2 = ((const float4*)W2)[lane];

    const int p = gw;
    if (p < 2044) {
      int i, j;
      if      (p < 512)  { i = 0;        j = p;        }
      else if (p < 1024) { i = 511;      j = p - 512;  }
      else if (p < 1534) { i = p - 1023; j = 0;        }
      else               { i = p - 1533; j = 511;      }

      const float4 a  = PA[i * H4 + lane];
      const float4 cu = PC[(i - 1) * H4 + lane];
      const float4 ed = PE[(i + 1) * H4 + lane];
      const float4 b  = PB[j * H4 + lane];
      const float4 du = PD[(j + 1) * H4 + lane];
      const float4 fd = PF[(j - 1) * H4 + lane];
      const float mu_m = (i >= 1 && j <= NN - 2) ? 1.f : 0.f;
      const float md_m = (i <= NN - 2 && j >= 1) ? 1.f : 0.f;

      float s0 = fmaf(md_m, ed.x + fd.x, fmaf(mu_m, cu.x + du.x, a.x + b.x));
      float s1 = fmaf(md_m, ed.y + fd.y, fmaf(mu_m, cu.y + du.y, a.y + b.y));
      float s2 = fmaf(md_m, ed.z + fd.z, fmaf(mu_m, cu.z + du.z, a.z + b.z));
      float s3 = fmaf(md_m, ed.w + fd.w, fmaf(mu_m, cu.w + du.w, a.w + b.w));

      float sum = (s0 + s1) + (s2 + s3);
      float ssq = fmaf(s0, s0, fmaf(s1, s1, fmaf(s2, s2, s3 * s3)));
#pragma unroll
      for (int off = 32; off >= 1; off >>= 1) {
        sum += __shfl_xor(sum, off, 64);
        ssq += __shfl_xor(ssq, off, 64);
      }
      const float mu  = sum * (1.f / HID);
      const float var = fmaf(ssq, 1.f / HID, -mu * mu);
      const float rs  = rsqrtf(var + 1e-5f);
      const float mrs = -mu * rs;

      auto nrm = [&](float s, float G, float Bt) {
        return fmaf(fmaf(s, rs, mrs), G, Bt);
      };
      float racc = fmaf(celu1(nrm(s0, g.x, be.x)), w2.x,
                   fmaf(celu1(nrm(s1, g.y, be.y)), w2.y,
                   fmaf(celu1(nrm(s2, g.z, be.z)), w2.z,
                        celu1(nrm(s3, g.w, be.w)) * w2.w)));
#pragma unroll
      for (int off = 32; off >= 1; off >>= 1)
        racc += __shfl_xor(racc, off, 64);
      if (lane == 0) out[i * NN + j] = racc + b2s;
    }
  }
}

extern "C" void kernel_launch(void* const* d_in, const int* in_sizes, int n_in,
                              void* d_out, int out_size, void* d_ws, size_t ws_size,
                              hipStream_t stream)
{
  const float* xl    = (const float*)d_in[0];
  const float* xr    = (const float*)d_in[1];
  const float* W1    = (const float*)d_in[2];
  const float* b1    = (const float*)d_in[3];
  const float* gamma = (const float*)d_in[4];
  const float* beta  = (const float*)d_in[5];
  const float* W2    = (const float*)d_in[6];
  const float* b2    = (const float*)d_in[7];
  float* out = (float*)d_out;

  float* P     = (float*)d_ws;                       // 3 MB
  float* Uf    = P + 6 * PSTRIDE;                    // 0.5 MB
  float* Vt    = Uf + NN * HID;                      // 0.5 MB (transposed V)
  float* Cross = Vt + NN * HID;                      // 1 MB
  unsigned short* Ubf = (unsigned short*)(Cross + NN * NN);
  unsigned short* Vbf = Ubf + NN * HID;
  float* rowstat = (float*)(Vbf + NN * HID);

  proj_kernel<<<dim3(NN / PROWS, 2), 256, 0, stream>>>(xl, xr, W1, b1, P);
  prep_kernel<<<NN, 256, 0, stream>>>(P, Uf, Vt, Ubf, Vbf, rowstat);
  cross_kernel<<<256, 256, 0, stream>>>(Ubf, Vbf, Cross);
  pair_kernel<<<NB_BORDER + 1020, 512, 0, stream>>>(P, Uf, Vt, Cross, rowstat,
                                                    gamma, beta, W2, b2, out);
}